// Round 4
// baseline (262.337 us; speedup 1.0000x reference)
//
#include <hip/hip_runtime.h>

// out[b, n] = sum_k x[b,k] * w[n,k]
// B=8, S=1, K=4096, N=11008, fp32.
// HBM-bound on the 180 MB weight stream (floor ~29 us at 6.3 TB/s).
//
// [Resubmission of round-3 kernel: previous bench aborted with "container
//  failed twice" (infra). Resource audit: 128 KiB static LDS <= 160 KiB/CU,
//  1024-thread block -> 128-VGPR budget vs ~80 live, grid 256x1024 legal.]
//
// Design (round-2 post-mortem): pure-stream kernel ran ~86 us (~2.1 TB/s)
// because x loads share the in-order vmcnt queue with weight loads -> every
// iteration's FMAs drain ALL outstanding weight loads (full ~900-cy HBM
// latency exposure per iteration). Fix:
//  - x (128 KB) staged into LDS ONCE per block (one barrier total). K-loop
//    x reads use lgkmcnt (ds_read_b128), weight loads keep vmcnt -> the
//    compiler can leave future weight loads in flight across iterations.
//  - grid = 256 blocks x 1024 threads = exactly 1 block/CU (128 KB LDS);
//    N = 11008 = 256*43 rows -> every CU owns exactly 43 rows (688 KB),
//    perfect makespan balance. 16 waves/CU.
//  - <=3 weight-row streams per wave, unroll-4 window -> ~12 weight loads
//    in flight per wave, 16 waves/CU >> the ~9 KB/CU needed for full BW.

#define BATCH 8
#define KDIM 4096
#define K4 (KDIM / 4)          // 1024 float4 per row
#define NDIM 11008
#define BLOCK 1024             // 16 waves
#define ROWS_PER_BLOCK 43      // 256 blocks * 43 = 11008 exactly
#define MAXR 3                 // ceil(43/16) row-slots per wave

__global__ __launch_bounds__(BLOCK)
void ActivationSparseLinear_4982162063725_kernel(const float* __restrict__ x,
                                                 const float* __restrict__ w,
                                                 float* __restrict__ out) {
    __shared__ float4 xs[BATCH * K4];   // 8192 float4 = 128 KB: ALL of x

    const int tid  = threadIdx.x;
    const int lane = tid & 63;
    const int wave = tid >> 6;

    const float4* xg4 = (const float4*)x;     // [BATCH][K4], linear 8192 float4
    const float4* wg4 = (const float4*)w;     // [NDIM][K4]

    // Stage the whole activation once: 8 coalesced 1024-lane float4 loads.
#pragma unroll
    for (int j = 0; j < BATCH; ++j)
        xs[j * K4 + tid] = xg4[j * K4 + tid];
    __syncthreads();                          // the only barrier in the kernel

    // Row assignment: wave owns local rows {wave, wave+16, wave+32} (< 43).
    const int nbase = blockIdx.x * ROWS_PER_BLOCK;
    bool valid[MAXR];
    const float4* wrow[MAXR];
#pragma unroll
    for (int r = 0; r < MAXR; ++r) {
        const int nl = wave + 16 * r;
        valid[r] = (nl < ROWS_PER_BLOCK);
        wrow[r] = wg4 + (size_t)(nbase + (valid[r] ? nl : 0)) * K4;
    }

    float acc[MAXR][BATCH];
#pragma unroll
    for (int r = 0; r < MAXR; ++r)
#pragma unroll
        for (int b = 0; b < BATCH; ++b) acc[r][b] = 0.0f;

    // 16 iterations cover K=4096 (64 lanes x 4 floats x 16). Weight loads are
    // the only vmcnt users; x comes from LDS on lgkmcnt.
#pragma unroll 4
    for (int i = 0; i < K4 / 64; ++i) {
        const int kk = i * 64 + lane;

        float4 wv[MAXR];                      // 3 coalesced 1 KB/wave streams
#pragma unroll
        for (int r = 0; r < MAXR; ++r) wv[r] = wrow[r][kk];

        float4 xv[BATCH];                     // ds_read_b128, conflict-free
#pragma unroll
        for (int b = 0; b < BATCH; ++b) xv[b] = xs[b * K4 + kk];

#pragma unroll
        for (int r = 0; r < MAXR; ++r)
#pragma unroll
            for (int b = 0; b < BATCH; ++b)
                acc[r][b] += wv[r].x * xv[b].x + wv[r].y * xv[b].y
                           + wv[r].z * xv[b].z + wv[r].w * xv[b].w;
    }

    // Butterfly-reduce each accumulator across the 64-lane wave.
#pragma unroll
    for (int r = 0; r < MAXR; ++r)
#pragma unroll
        for (int b = 0; b < BATCH; ++b) {
            float v = acc[r][b];
#pragma unroll
            for (int off = 32; off > 0; off >>= 1)
                v += __shfl_xor(v, off, 64);
            acc[r][b] = v;
        }

    if (lane == 0) {
#pragma unroll
        for (int r = 0; r < MAXR; ++r)
            if (valid[r]) {
                const int n = nbase + wave + 16 * r;
#pragma unroll
                for (int b = 0; b < BATCH; ++b)
                    out[(size_t)b * NDIM + n] = acc[r][b];
            }
    }
}

extern "C" void kernel_launch(void* const* d_in, const int* in_sizes, int n_in,
                              void* d_out, int out_size, void* d_ws, size_t ws_size,
                              hipStream_t stream) {
    const float* x = (const float*)d_in[0];   // (8, 1, 4096) fp32
    const float* w = (const float*)d_in[1];   // (11008, 4096) fp32
    float* out = (float*)d_out;               // (8, 1, 11008) fp32

    dim3 grid(NDIM / ROWS_PER_BLOCK);         // 256 blocks = 1 per CU
    ActivationSparseLinear_4982162063725_kernel<<<grid, BLOCK, 0, stream>>>(x, w, out);
}

// Round 5
// 244.013 us; speedup vs baseline: 1.0751x; 1.0751x over previous
//
#include <hip/hip_runtime.h>

// out[b, n] = sum_k x[b,k] * w[n,k]
// B=8, S=1, K=4096, N=11008, fp32.
// HBM-bound on the 180 MB weight stream (floor ~29 us at 6.3 TB/s).
//
// Round-4 post-mortem: three structurally different kernels (r0 LDS-chunked,
// r2 pure-stream, r4 decoupled/balanced) all plateau at ~2.1-2.3 TB/s weight
// bandwidth while the harness fill hits 6.8 TB/s. Shared trait: ~11008
// concurrent row-streams advancing in interleaved 1-KB wave-loads -> DRAM
// row-buffer thrash. This round keeps r0's scaffold (best: ~80 us) and
// changes ONLY the weight issue order: per K-chunk each wave issues row0's
// 4-KB chunk as 4 back-to-back 1-KB loads (one contiguous burst), then
// row1's, THEN computes from LDS. Per-stream burst 1 KB -> 4 KB, streams
// de-interleaved at issue time.

#define BATCH 8
#define KDIM 4096
#define K4 (KDIM / 4)         // 1024 float4 per weight row
#define NDIM 11008
#define KC 1024               // K-chunk staged into LDS (8*1024*4 = 32 KB)
#define KC4 (KC / 4)          // 256 float4 per batch per chunk
#define BLOCK 256             // 4 waves
#define ROWS_PER_WAVE 2
#define ROWS_PER_BLOCK 8      // 4 waves * 2 rows

__global__ __launch_bounds__(BLOCK)   // no 2nd arg: r1's spill lesson
void ActivationSparseLinear_4982162063725_kernel(const float* __restrict__ x,
                                                 const float* __restrict__ w,
                                                 float* __restrict__ out) {
    __shared__ float4 xs[BATCH * KC4];   // 8 batches x 256 float4 = 32 KB

    const int tid  = threadIdx.x;
    const int lane = tid & 63;
    const int wave = tid >> 6;
    const int n0   = blockIdx.x * ROWS_PER_BLOCK + wave * ROWS_PER_WAVE;

    const float4* xg4 = (const float4*)x;     // [BATCH][K4]
    const float4* wg4 = (const float4*)w;     // [NDIM][K4]

    float acc[ROWS_PER_WAVE][BATCH];
#pragma unroll
    for (int r = 0; r < ROWS_PER_WAVE; ++r)
#pragma unroll
        for (int b = 0; b < BATCH; ++b) acc[r][b] = 0.0f;

    const float4* wrow0 = wg4 + (size_t)(n0 + 0) * K4;
    const float4* wrow1 = wg4 + (size_t)(n0 + 1) * K4;

    for (int c = 0; c < KDIM / KC; ++c) {     // 4 chunks
        // Stage x[:, c*KC .. c*KC+KC) into LDS: 8 coalesced 256-lane float4
        // loads (KC4 == BLOCK, so batch j maps exactly to pass j).
#pragma unroll
        for (int j = 0; j < BATCH; ++j)
            xs[j * KC4 + tid] = xg4[j * K4 + c * KC4 + tid];
        __syncthreads();

        const int cb = c * KC4;

        // Burst-issue the chunk's weight loads: 4 back-to-back 1-KB loads per
        // row = one contiguous 4-KB stream burst per row, rows NOT interleaved.
        float4 wa[4], wb[4];
#pragma unroll
        for (int i = 0; i < 4; ++i) wa[i] = wrow0[cb + i * 64 + lane];
#pragma unroll
        for (int i = 0; i < 4; ++i) wb[i] = wrow1[cb + i * 64 + lane];

        // Compute phase: x from LDS (lgkmcnt), weights drain with staged vmcnt.
#pragma unroll
        for (int i = 0; i < 4; ++i) {
            float4 xv[BATCH];
#pragma unroll
            for (int b = 0; b < BATCH; ++b)
                xv[b] = xs[b * KC4 + i * 64 + lane];   // conflict-free b128

#pragma unroll
            for (int b = 0; b < BATCH; ++b) {
                acc[0][b] += wa[i].x * xv[b].x + wa[i].y * xv[b].y
                           + wa[i].z * xv[b].z + wa[i].w * xv[b].w;
                acc[1][b] += wb[i].x * xv[b].x + wb[i].y * xv[b].y
                           + wb[i].z * xv[b].z + wb[i].w * xv[b].w;
            }
        }
        __syncthreads();
    }

    // Butterfly-reduce each accumulator across the 64-lane wave.
#pragma unroll
    for (int r = 0; r < ROWS_PER_WAVE; ++r)
#pragma unroll
        for (int b = 0; b < BATCH; ++b) {
            float v = acc[r][b];
#pragma unroll
            for (int off = 32; off > 0; off >>= 1)
                v += __shfl_xor(v, off, 64);
            acc[r][b] = v;
        }

    if (lane == 0) {
#pragma unroll
        for (int r = 0; r < ROWS_PER_WAVE; ++r)
#pragma unroll
            for (int b = 0; b < BATCH; ++b)
                out[(size_t)b * NDIM + n0 + r] = acc[r][b];
    }
}

extern "C" void kernel_launch(void* const* d_in, const int* in_sizes, int n_in,
                              void* d_out, int out_size, void* d_ws, size_t ws_size,
                              hipStream_t stream) {
    const float* x = (const float*)d_in[0];   // (8, 1, 4096) fp32
    const float* w = (const float*)d_in[1];   // (11008, 4096) fp32
    float* out = (float*)d_out;               // (8, 1, 11008) fp32

    dim3 grid(NDIM / ROWS_PER_BLOCK);         // 1376 blocks, exact fit
    ActivationSparseLinear_4982162063725_kernel<<<grid, BLOCK, 0, stream>>>(x, w, out);
}

// Round 6
// 240.380 us; speedup vs baseline: 1.0913x; 1.0151x over previous
//
#include <hip/hip_runtime.h>

// out[b, n] = sum_k x[b,k] * w[n,k]
// B=8, S=1, K=4096, N=11008, fp32.
// HBM-bound on the 180 MB weight stream.
//
// Round-5 post-mortem: burst reorder was null (244.0 vs 245.3 us). Four
// structurally different schedules (chunked/pure-stream/decoupled/burst) all
// plateau at 2.1-2.4 TB/s weight read BW despite ample outstanding-load
// capacity -> the shared trait left is that every weight line is a
// 100%-miss L2-ALLOCATING read (zero reuse, pure pollution). This round:
// identical structure to r5, weights switched to __builtin_nontemporal_load
// (nt bit: bypass L1/L2 allocation). x keeps normal cached loads and is no
// longer evicted by the weight stream. Clean A/B vs r5: any delta is NT.

#define BATCH 8
#define KDIM 4096
#define K4 (KDIM / 4)         // 1024 float4 per weight row
#define NDIM 11008
#define KC 1024               // K-chunk staged into LDS (8*1024*4 = 32 KB)
#define KC4 (KC / 4)          // 256 float4 per batch per chunk
#define BLOCK 256             // 4 waves
#define ROWS_PER_WAVE 2
#define ROWS_PER_BLOCK 8      // 4 waves * 2 rows

typedef float f4 __attribute__((ext_vector_type(4)));

__global__ __launch_bounds__(BLOCK)
void ActivationSparseLinear_4982162063725_kernel(const float* __restrict__ x,
                                                 const float* __restrict__ w,
                                                 float* __restrict__ out) {
    __shared__ float4 xs[BATCH * KC4];   // 8 batches x 256 float4 = 32 KB

    const int tid  = threadIdx.x;
    const int lane = tid & 63;
    const int wave = tid >> 6;
    const int n0   = blockIdx.x * ROWS_PER_BLOCK + wave * ROWS_PER_WAVE;

    const float4* xg4 = (const float4*)x;     // [BATCH][K4]
    const f4* wg4 = (const f4*)w;             // [NDIM][K4]

    float acc[ROWS_PER_WAVE][BATCH];
#pragma unroll
    for (int r = 0; r < ROWS_PER_WAVE; ++r)
#pragma unroll
        for (int b = 0; b < BATCH; ++b) acc[r][b] = 0.0f;

    const f4* wrow0 = wg4 + (size_t)(n0 + 0) * K4;
    const f4* wrow1 = wg4 + (size_t)(n0 + 1) * K4;

    for (int c = 0; c < KDIM / KC; ++c) {     // 4 chunks
        // Stage x[:, c*KC .. c*KC+KC) into LDS: 8 coalesced 256-lane float4
        // loads (normal cached loads -- x is the one thing that WANTS L2).
#pragma unroll
        for (int j = 0; j < BATCH; ++j)
            xs[j * KC4 + tid] = xg4[j * K4 + c * KC4 + tid];
        __syncthreads();

        const int cb = c * KC4;

        // Weight loads: nontemporal (nt) -- no L1/L2 allocation for a
        // zero-reuse stream. 4 back-to-back 1-KB loads per row.
        f4 wa[4], wb[4];
#pragma unroll
        for (int i = 0; i < 4; ++i)
            wa[i] = __builtin_nontemporal_load(wrow0 + cb + i * 64 + lane);
#pragma unroll
        for (int i = 0; i < 4; ++i)
            wb[i] = __builtin_nontemporal_load(wrow1 + cb + i * 64 + lane);

        // Compute phase: x from LDS (lgkmcnt), weights drain with staged vmcnt.
#pragma unroll
        for (int i = 0; i < 4; ++i) {
            float4 xv[BATCH];
#pragma unroll
            for (int b = 0; b < BATCH; ++b)
                xv[b] = xs[b * KC4 + i * 64 + lane];   // conflict-free b128

#pragma unroll
            for (int b = 0; b < BATCH; ++b) {
                acc[0][b] += wa[i][0] * xv[b].x + wa[i][1] * xv[b].y
                           + wa[i][2] * xv[b].z + wa[i][3] * xv[b].w;
                acc[1][b] += wb[i][0] * xv[b].x + wb[i][1] * xv[b].y
                           + wb[i][2] * xv[b].z + wb[i][3] * xv[b].w;
            }
        }
        __syncthreads();
    }

    // Butterfly-reduce each accumulator across the 64-lane wave.
#pragma unroll
    for (int r = 0; r < ROWS_PER_WAVE; ++r)
#pragma unroll
        for (int b = 0; b < BATCH; ++b) {
            float v = acc[r][b];
#pragma unroll
            for (int off = 32; off > 0; off >>= 1)
                v += __shfl_xor(v, off, 64);
            acc[r][b] = v;
        }

    if (lane == 0) {
#pragma unroll
        for (int r = 0; r < ROWS_PER_WAVE; ++r)
#pragma unroll
            for (int b = 0; b < BATCH; ++b)
                out[(size_t)b * NDIM + n0 + r] = acc[r][b];
    }
}

extern "C" void kernel_launch(void* const* d_in, const int* in_sizes, int n_in,
                              void* d_out, int out_size, void* d_ws, size_t ws_size,
                              hipStream_t stream) {
    const float* x = (const float*)d_in[0];   // (8, 1, 4096) fp32
    const float* w = (const float*)d_in[1];   // (11008, 4096) fp32
    float* out = (float*)d_out;               // (8, 1, 11008) fp32

    dim3 grid(NDIM / ROWS_PER_BLOCK);         // 1376 blocks, exact fit
    ActivationSparseLinear_4982162063725_kernel<<<grid, BLOCK, 0, stream>>>(x, w, out);
}